// Round 12
// baseline (314.743 us; speedup 1.0000x reference)
//
#include <hip/hip_runtime.h>
#include <math.h>

#define B_ 4
#define C_ 512
#define D_ 128
#define N_ 4096

typedef short s4v __attribute__((ext_vector_type(4)));
typedef short s8v __attribute__((ext_vector_type(8)));
typedef float f4v __attribute__((ext_vector_type(4)));

__device__ __forceinline__ unsigned short f2bf(float x) {
    union { float f; unsigned u; } v; v.f = x;
    unsigned r = v.u + 0x7FFF + ((v.u >> 16) & 1);   // RNE
    return (unsigned short)(r >> 16);
}
__device__ __forceinline__ float bf2f(unsigned short h) {
    union { unsigned u; float f; } v; v.u = ((unsigned)h) << 16; return v.f;
}

// ---------------------------------------------------------------------------
// W/bias pre-convert: Wb rows [0:64]=Wq | [64:128]=Wk | [128:640]=Wv |
// [640:704]=Wdq | [704:768]=Wdk (bf16, row-major 512). biasb same order f32.
// ---------------------------------------------------------------------------
__global__ __launch_bounds__(256) void cvt_w_kernel(
    const float* __restrict__ Wq,  const float* __restrict__ bq,
    const float* __restrict__ Wk,  const float* __restrict__ bk,
    const float* __restrict__ Wdq, const float* __restrict__ bdq,
    const float* __restrict__ Wdk, const float* __restrict__ bdk,
    const float* __restrict__ Wv,  const float* __restrict__ bv,
    unsigned short* __restrict__ Wb, float* __restrict__ biasb)
{
    int t = blockIdx.x * 256 + threadIdx.x;        // 192 blocks
    int e0 = t * 8;
    int row = e0 >> 9, c = e0 & 511;
    const float* src; int r0;
    if (row < 64)       { src = Wq;  r0 = row; }
    else if (row < 128) { src = Wk;  r0 = row - 64; }
    else if (row < 640) { src = Wv;  r0 = row - 128; }
    else if (row < 704) { src = Wdq; r0 = row - 640; }
    else                { src = Wdk; r0 = row - 704; }
    const float* p = src + (size_t)r0 * 512 + c;
    s8v o;
    #pragma unroll
    for (int u = 0; u < 8; ++u) ((unsigned short*)&o)[u] = f2bf(p[u]);
    *(s8v*)&Wb[e0] = o;
    if (blockIdx.x == 0) {
        #pragma unroll
        for (int s = 0; s < 3; ++s) {
            int o2 = threadIdx.x + 256 * s;
            float v;
            if (o2 < 64)       v = bq[o2];
            else if (o2 < 128) v = bk[o2 - 64];
            else if (o2 < 640) v = bv[o2 - 128];
            else if (o2 < 704) v = bdq[o2 - 640];
            else               v = bdk[o2 - 704];
            biasb[o2] = v;
        }
    }
}

// ---------------------------------------------------------------------------
// Projection GEMM with FUSED transpose-convert (byte-exact R14 — fastest
// measured; R16's V LDS-bounce store was neutral and is reverted).
// ---------------------------------------------------------------------------
__global__ __launch_bounds__(256) void gemm_kernel(
    const unsigned short* __restrict__ Wb, const float* __restrict__ biasb,
    const float* __restrict__ x_rgb, const float* __restrict__ x_dep,
    unsigned short* __restrict__ Q, unsigned short* __restrict__ K,
    unsigned short* __restrict__ V)
{
    __shared__ __align__(16) unsigned short Ws[128 * 64];
    __shared__ __align__(16) unsigned short Xs[128 * 72];
    const int b  = blockIdx.x >> 5;
    const int i0 = (blockIdx.x & 31) * 128;
    const int by = blockIdx.y;
    const int mbase = by * 128;
    const int st = (by == 5);
    const int t = threadIdx.x, w = t >> 6;
    const int lane = t & 63, col = lane & 15, quad = lane >> 4;
    const int mh = (w & 1) * 64, nh = (w >> 1) * 64;
    const int c4x = t >> 4, i4x = t & 15;      // staging decode: 16c x 16i

    const unsigned short* Wg = Wb + (size_t)mbase * 512;
    const float* Xsrc = (st ? x_dep : x_rgb) + (size_t)b * C_ * N_;

    f4v acc[4][4];
    #pragma unroll
    for (int mt = 0; mt < 4; ++mt)
        #pragma unroll
        for (int nt = 0; nt < 4; ++nt) acc[mt][nt] = (f4v){0.f, 0.f, 0.f, 0.f};

    for (int kc = 0; kc < 8; ++kc) {
        const int k0 = kc * 64;
        s8v wt[4];
        float4 xr[2][4];
        #pragma unroll
        for (int s = 0; s < 4; ++s) {
            int lin = t + 256 * s;
            int row = lin >> 3, g = lin & 7;
            wt[s] = *(const s8v*)&Wg[(size_t)row * 512 + k0 + g * 8];
        }
        #pragma unroll
        for (int ih2 = 0; ih2 < 2; ++ih2) {
            const float* xp = Xsrc + (size_t)(k0 + c4x * 4) * N_
                            + i0 + ih2 * 64 + i4x * 4;
            xr[ih2][0] = *(const float4*)(xp);
            xr[ih2][1] = *(const float4*)(xp + N_);
            xr[ih2][2] = *(const float4*)(xp + 2 * N_);
            xr[ih2][3] = *(const float4*)(xp + 3 * N_);
        }
        __syncthreads();                       // prior iter's frag reads done
        #pragma unroll
        for (int s = 0; s < 4; ++s) {
            int lin = t + 256 * s;
            int row = lin >> 3, g = lin & 7;
            int soff = row * 64 + ((g ^ (row & 7)) * 8);
            *(s8v*)&Ws[soff] = wt[s];
        }
        #pragma unroll
        for (int ih2 = 0; ih2 < 2; ++ih2) {
            #pragma unroll
            for (int j = 0; j < 4; ++j) {
                s4v pj = { (short)f2bf(xr[ih2][0][j]), (short)f2bf(xr[ih2][1][j]),
                           (short)f2bf(xr[ih2][2][j]), (short)f2bf(xr[ih2][3][j]) };
                *(s4v*)&Xs[(ih2 * 64 + i4x * 4 + j) * 72 + c4x * 4] = pj;
            }
        }
        __syncthreads();                       // tile staged
        #pragma unroll
        for (int kk = 0; kk < 2; ++kk) {
            const int gq = kk * 4 + quad;
            s8v af[4], bf[4];
            #pragma unroll
            for (int mt = 0; mt < 4; ++mt) {
                int r = mh + mt * 16 + col;
                af[mt] = *(const s8v*)&Ws[r * 64 + ((gq ^ (r & 7)) * 8)];
            }
            #pragma unroll
            for (int nt = 0; nt < 4; ++nt) {
                int r = nh + nt * 16 + col;
                bf[nt] = *(const s8v*)&Xs[r * 72 + gq * 8];
            }
            #pragma unroll
            for (int nt = 0; nt < 4; ++nt)
                #pragma unroll
                for (int mt = 0; mt < 4; ++mt)
                    acc[mt][nt] = __builtin_amdgcn_mfma_f32_16x16x32_bf16(
                        af[mt], bf[nt], acc[mt][nt], 0, 0, 0);
        }
    }

    // ---- epilogue ----
    const int mlo0 = mbase + mh;               // wave-uniform
    #pragma unroll
    for (int mt = 0; mt < 4; ++mt) {
        const int mlo = mlo0 + mt * 16;
        f4v bi = *(const f4v*)&biasb[mlo + quad * 4];
        if (mlo < 128 || mlo >= 640) {         // Q/K rows
            unsigned short* dst; int dbase;
            if (mlo < 64)       { dst = Q; dbase = mlo; }
            else if (mlo < 128) { dst = K; dbase = mlo - 64; }
            else if (mlo < 704) { dst = Q; dbase = 64 + (mlo - 640); }
            else                { dst = K; dbase = 64 + (mlo - 704); }
            #pragma unroll
            for (int nt = 0; nt < 4; ++nt) {
                int i = i0 + nh + nt * 16 + col;
                s4v pk = { (short)f2bf(acc[mt][nt][0] + bi[0]),
                           (short)f2bf(acc[mt][nt][1] + bi[1]),
                           (short)f2bf(acc[mt][nt][2] + bi[2]),
                           (short)f2bf(acc[mt][nt][3] + bi[3]) };
                *(s4v*)&dst[((size_t)b * N_ + i) * D_ + dbase + quad * 4] = pk;
            }
        } else {                               // V rows
            int c0 = mlo - 128 + quad * 4;
            #pragma unroll
            for (int nt = 0; nt < 4; ++nt) {
                int i = i0 + nh + nt * 16 + col;
                #pragma unroll
                for (int r = 0; r < 4; ++r)
                    V[((size_t)b * C_ + c0 + r) * N_ + i] =
                        f2bf(acc[mt][nt][r] + bi[r]);
            }
        }
    }
}

// ---------------------------------------------------------------------------
// MFMA flash attention, R17: NO j-split. Block = (b, 32-row i-tile), grid 512
// (same count, same 2 blocks/CU), iterating ALL 128 j-tiles. Chip-wide
// MFMA/exp/load work identical to R12 (QK 17.2 GF, PV 68.7 GF, each once —
// unlike R13's x4 duplication). Each block owns complete softmax rows ->
// normalize in f32 (more precise than old bf16 round-trip), add x_rgb,
// write out DIRECTLY. combine_kernel + O_ws + l_ws DELETED.
// Loop body = frozen R12 skeleton mechanically halved: 3 lgkm-only barriers,
// no vmcnt(0), kt oldest-first, Vs write after QK+softmax, same swizzles,
// setprio on PV. accO[2][8] = 64 AGPR (was 128).
// Epilogue: per-wave LDS bounce through dead Vs (stride-36 f32 + XOR slot
// swizzle) -> fully-coalesced 128B fp32 out rows; x_rgb residual fused.
// XCD: id&7 = (b, it-parity) -> per-XCD working set K_b 1MB + V_b 4.2MB
// (slightly over 4MB L2 -> partial L3 spill, accepted).
// LDS: Ks 8704 | Ps[32*40] 2560 | Vs 32768 | lred 256 = 44288 B.
// ---------------------------------------------------------------------------
__global__ __launch_bounds__(256, 2) void attn_kernel(
    const unsigned short* __restrict__ Q, const unsigned short* __restrict__ K,
    const unsigned short* __restrict__ V,
    const float* __restrict__ x_rgb, const float* __restrict__ gamma,
    float* __restrict__ out)
{
    __shared__ __align__(16) unsigned short Ks[32 * 136];
    __shared__ __align__(16) unsigned short Ps[32 * 40];
    __shared__ __align__(16) unsigned short Vs[512 * 32];
    __shared__ float lred[2][32];

    const int id  = blockIdx.x;             // 512 flat
    const int grp = id & 7;                 // XCD-affine: (b, it-parity)
    const int b   = grp & 3;
    const int itl = grp >> 2;
    const int it  = (id >> 3) * 2 + itl;    // 0..127
    const int i0  = it * 32;
    const int t = threadIdx.x, w = t >> 6;
    const int lane = t & 63, col = lane & 15, quad = lane >> 4;
    const int ih = w & 1, jq = w >> 1;

    const unsigned short* Kg = K + (size_t)b * N_ * D_;
    const unsigned short* Vg = V + (size_t)b * C_ * N_;

    s8v qf[4];
    {
        const unsigned short* qr =
            Q + ((size_t)b * N_ + i0 + ih * 16 + col) * D_ + quad * 8;
        #pragma unroll
        for (int kk = 0; kk < 4; ++kk) qf[kk] = *(const s8v*)(qr + kk * 32);
    }

    f4v accO[2][8];
    #pragma unroll
    for (int rt = 0; rt < 2; ++rt)
        #pragma unroll
        for (int ct = 0; ct < 8; ++ct) accO[rt][ct] = (f4v){0.f, 0.f, 0.f, 0.f};
    float lsum = 0.f;

    for (int tt = 0; tt < 128; ++tt) {
        const int j0 = tt * 32;
        // issue loads: kt FIRST (oldest -> Ks write waits vmcnt(8) = kt only)
        s8v kt[2], vt[8];
        #pragma unroll
        for (int s = 0; s < 2; ++s) {
            int gi = t + 256 * s;
            kt[s] = *(const s8v*)&Kg[(size_t)(j0 + (gi >> 4)) * D_ + (gi & 15) * 8];
        }
        #pragma unroll
        for (int s = 0; s < 8; ++s) {
            int gi = t + 256 * s;
            vt[s] = *(const s8v*)&Vg[(size_t)(gi >> 2) * N_ + j0 + (gi & 3) * 8];
        }
        // B1: prior iter's Vs/Ps/Ks reads complete
        asm volatile("s_waitcnt lgkmcnt(0)" ::: "memory");
        __builtin_amdgcn_s_barrier();
        // stage K tile (vmcnt(8): waits kt, vt stays in flight)
        #pragma unroll
        for (int s = 0; s < 2; ++s) {
            int gi = t + 256 * s;
            *(s8v*)&Ks[(gi >> 4) * 136 + (gi & 15) * 8] = kt[s];
        }
        // B2: K tile staged
        asm volatile("s_waitcnt lgkmcnt(0)" ::: "memory");
        __builtin_amdgcn_s_barrier();
        // QK^T (one 16x16 quadrant per wave: (ih, jq))
        f4v s0 = (f4v){0.f, 0.f, 0.f, 0.f};
        #pragma unroll
        for (int kk = 0; kk < 4; ++kk) {
            s8v kf = *(const s8v*)&Ks[(jq * 16 + col) * 136 + kk * 32 + quad * 8];
            s0 = __builtin_amdgcn_mfma_f32_16x16x32_bf16(kf, qf[kk], s0, 0, 0, 0);
        }
        // softmax partials + pack P
        {
            s4v p; float ls = 0.f;
            #pragma unroll
            for (int r = 0; r < 4; ++r) {
                float e = __expf(s0[r]);
                ls += e;
                p[r] = (short)f2bf(e);
            }
            lsum += ls;
            *(s4v*)&Ps[(ih * 16 + col) * 40 + jq * 16 + quad * 4] = p;
        }
        // stage V tile (vmcnt wait for vt covered by QK+softmax above)
        #pragma unroll
        for (int s = 0; s < 8; ++s) {
            int gi = t + 256 * s;
            int c = gi >> 2, g = gi & 3;
            int sw = (g + c + (c >> 2)) & 3;
            *(s8v*)&Vs[c * 32 + sw * 8] = vt[s];
        }
        // B3: P + V visible
        asm volatile("s_waitcnt lgkmcnt(0)" ::: "memory");
        __builtin_amdgcn_s_barrier();
        // P fragments + PV
        s8v pf[2];
        #pragma unroll
        for (int rt = 0; rt < 2; ++rt)
            pf[rt] = *(const s8v*)&Ps[(rt * 16 + col) * 40 + quad * 8];
        __builtin_amdgcn_s_setprio(1);
        #pragma unroll
        for (int ct = 0; ct < 8; ++ct) {
            int row = w * 128 + ct * 16 + col;
            int sw = (quad + row + (row >> 2)) & 3;
            s8v vf = *(const s8v*)&Vs[row * 32 + sw * 8];
            #pragma unroll
            for (int rt = 0; rt < 2; ++rt)
                accO[rt][ct] = __builtin_amdgcn_mfma_f32_16x16x32_bf16(pf[rt], vf, accO[rt][ct], 0, 0, 0);
        }
        __builtin_amdgcn_s_setprio(0);
    }

    // ---- l reduction (row sums over all j) ----
    {
        float v = lsum;
        v += __shfl_xor(v, 16);
        v += __shfl_xor(v, 32);
        if (quad == 0) lred[jq][ih * 16 + col] = v;
    }
    __syncthreads();                       // also: Vs/Ks now dead -> scratch

    // ---- fused normalize + residual + coalesced out store ----
    // Per-wave f32 scratch in Vs: 32 c-rows x 32 i, stride 36 (16B-aligned,
    // 2-way banks), slot-XOR on the i-group axis. 4 rounds cover 128 c.
    const float g = gamma[0];
    float* Tw = (float*)((char*)Vs + w * 4608);
    float4 lq0 = *(const float4*)&lred[0][quad * 4];        // rt=0 rows
    float4 lq1 = *(const float4*)&lred[1][quad * 4];
    float4 lq2 = *(const float4*)&lred[0][16 + quad * 4];   // rt=1 rows
    float4 lq3 = *(const float4*)&lred[1][16 + quad * 4];
    float4 linv0 = { 1.f / (lq0.x + lq1.x), 1.f / (lq0.y + lq1.y),
                     1.f / (lq0.z + lq1.z), 1.f / (lq0.w + lq1.w) };
    float4 linv1 = { 1.f / (lq2.x + lq3.x), 1.f / (lq2.y + lq3.y),
                     1.f / (lq2.z + lq3.z), 1.f / (lq2.w + lq3.w) };
    #pragma unroll
    for (int cc = 0; cc < 4; ++cc) {
        #pragma unroll
        for (int u = 0; u < 2; ++u) {
            const int ct = cc * 2 + u;
            const int lc = u * 16 + col;                  // 0..31
            #pragma unroll
            for (int rt = 0; rt < 2; ++rt) {
                const float4 li = rt ? linv1 : linv0;
                const int slot = (rt * 4 + quad) ^ (lc & 7);
                float4 val = { g * accO[rt][ct][0] * li.x,
                               g * accO[rt][ct][1] * li.y,
                               g * accO[rt][ct][2] * li.z,
                               g * accO[rt][ct][3] * li.w };
                *(float4*)&Tw[lc * 36 + slot * 4] = val;
            }
        }
        asm volatile("s_waitcnt lgkmcnt(0)" ::: "memory");   // same-wave
        const int gr = lane & 7, csl = lane >> 3;
        #pragma unroll
        for (int p = 0; p < 4; ++p) {
            const int lc = p * 8 + csl;                   // 0..31
            const int slot = gr ^ (lc & 7);               // holds i-group gr
            float4 o4 = *(const float4*)&Tw[lc * 36 + slot * 4];
            const int c = w * 128 + cc * 32 + lc;
            size_t base = ((size_t)b * C_ + c) * N_ + i0 + gr * 4;
            float4 x4 = *(const float4*)&x_rgb[base];
            float4 r4 = { o4.x + x4.x, o4.y + x4.y, o4.z + x4.z, o4.w + x4.w };
            *(float4*)&out[base] = r4;
        }
        asm volatile("s_waitcnt lgkmcnt(0)" ::: "memory");   // WAR before next
    }
}

// ---------------------------------------------------------------------------
extern "C" void kernel_launch(void* const* d_in, const int* in_sizes, int n_in,
                              void* d_out, int out_size, void* d_ws, size_t ws_size,
                              hipStream_t stream) {
    (void)in_sizes; (void)n_in; (void)out_size; (void)ws_size;
    const float* x_rgb = (const float*)d_in[0];
    const float* x_dep = (const float*)d_in[1];
    const float* Wq    = (const float*)d_in[2];
    const float* bq    = (const float*)d_in[3];
    const float* Wk    = (const float*)d_in[4];
    const float* bk    = (const float*)d_in[5];
    const float* Wdq   = (const float*)d_in[6];
    const float* bdq   = (const float*)d_in[7];
    const float* Wdk   = (const float*)d_in[8];
    const float* bdk   = (const float*)d_in[9];
    const float* Wv    = (const float*)d_in[10];
    const float* bv    = (const float*)d_in[11];
    const float* gamma = (const float*)d_in[12];
    float* out = (float*)d_out;

    // ws: Q 4MB | K 4MB | V 16.8MB | Wb 768KB | biasb 4KB f32.
    // O_ws / l_ws eliminated (R17: attn writes out directly).
    unsigned short* Q     = (unsigned short*)d_ws;
    unsigned short* K     = Q + (size_t)B_ * N_ * D_;
    unsigned short* V     = K + (size_t)B_ * N_ * D_;
    unsigned short* Wb    = V + (size_t)B_ * C_ * N_;
    float*          biasb = (float*)(Wb + 768 * 512);

    cvt_w_kernel<<<dim3(192), 256, 0, stream>>>(
        Wq, bq, Wk, bk, Wdq, bdq, Wdk, bdk, Wv, bv, Wb, biasb);
    gemm_kernel<<<dim3(128, 6), 256, 0, stream>>>(Wb, biasb, x_rgb, x_dep, Q, K, V);
    attn_kernel<<<dim3(512), 256, 0, stream>>>(Q, K, V, x_rgb, gamma, out);
}

// Round 13
// 272.973 us; speedup vs baseline: 1.1530x; 1.1530x over previous
//
#include <hip/hip_runtime.h>
#include <math.h>

#define B_ 4
#define C_ 512
#define D_ 128
#define N_ 4096

typedef short s4v __attribute__((ext_vector_type(4)));
typedef short s8v __attribute__((ext_vector_type(8)));
typedef float f4v __attribute__((ext_vector_type(4)));

__device__ __forceinline__ unsigned short f2bf(float x) {
    union { float f; unsigned u; } v; v.f = x;
    unsigned r = v.u + 0x7FFF + ((v.u >> 16) & 1);   // RNE
    return (unsigned short)(r >> 16);
}
__device__ __forceinline__ float bf2f(unsigned short h) {
    union { unsigned u; float f; } v; v.u = ((unsigned)h) << 16; return v.f;
}

// ---------------------------------------------------------------------------
// W/bias pre-convert: Wb rows [0:64]=Wq | [64:128]=Wk | [128:640]=Wv |
// [640:704]=Wdq | [704:768]=Wdk (bf16, row-major 512). biasb same order f32.
// ---------------------------------------------------------------------------
__global__ __launch_bounds__(256) void cvt_w_kernel(
    const float* __restrict__ Wq,  const float* __restrict__ bq,
    const float* __restrict__ Wk,  const float* __restrict__ bk,
    const float* __restrict__ Wdq, const float* __restrict__ bdq,
    const float* __restrict__ Wdk, const float* __restrict__ bdk,
    const float* __restrict__ Wv,  const float* __restrict__ bv,
    unsigned short* __restrict__ Wb, float* __restrict__ biasb)
{
    int t = blockIdx.x * 256 + threadIdx.x;        // 192 blocks
    int e0 = t * 8;
    int row = e0 >> 9, c = e0 & 511;
    const float* src; int r0;
    if (row < 64)       { src = Wq;  r0 = row; }
    else if (row < 128) { src = Wk;  r0 = row - 64; }
    else if (row < 640) { src = Wv;  r0 = row - 128; }
    else if (row < 704) { src = Wdq; r0 = row - 640; }
    else                { src = Wdk; r0 = row - 704; }
    const float* p = src + (size_t)r0 * 512 + c;
    s8v o;
    #pragma unroll
    for (int u = 0; u < 8; ++u) ((unsigned short*)&o)[u] = f2bf(p[u]);
    *(s8v*)&Wb[e0] = o;
    if (blockIdx.x == 0) {
        #pragma unroll
        for (int s = 0; s < 3; ++s) {
            int o2 = threadIdx.x + 256 * s;
            float v;
            if (o2 < 64)       v = bq[o2];
            else if (o2 < 128) v = bk[o2 - 64];
            else if (o2 < 640) v = bv[o2 - 128];
            else if (o2 < 704) v = bdq[o2 - 640];
            else               v = bdk[o2 - 704];
            biasb[o2] = v;
        }
    }
}

// ---------------------------------------------------------------------------
// Projection GEMM with FUSED transpose-convert (byte-exact R14 — session
// best, 272.8us total). X staged directly from x fp32 [b][c][i] with
// in-register f2bf transpose into Xs[128][72]; Ws path XOR-swizzled bf16.
// R16's V LDS-bounce was neutral -> reverted; R11's pipeline surgery
// regressed at 12 waves/SIMD (TLP already covers drains) -> plain
// __syncthreads kept.
// ---------------------------------------------------------------------------
__global__ __launch_bounds__(256) void gemm_kernel(
    const unsigned short* __restrict__ Wb, const float* __restrict__ biasb,
    const float* __restrict__ x_rgb, const float* __restrict__ x_dep,
    unsigned short* __restrict__ Q, unsigned short* __restrict__ K,
    unsigned short* __restrict__ V)
{
    __shared__ __align__(16) unsigned short Ws[128 * 64];
    __shared__ __align__(16) unsigned short Xs[128 * 72];
    const int b  = blockIdx.x >> 5;
    const int i0 = (blockIdx.x & 31) * 128;
    const int by = blockIdx.y;
    const int mbase = by * 128;
    const int st = (by == 5);
    const int t = threadIdx.x, w = t >> 6;
    const int lane = t & 63, col = lane & 15, quad = lane >> 4;
    const int mh = (w & 1) * 64, nh = (w >> 1) * 64;
    const int c4x = t >> 4, i4x = t & 15;      // staging decode: 16c x 16i

    const unsigned short* Wg = Wb + (size_t)mbase * 512;
    const float* Xsrc = (st ? x_dep : x_rgb) + (size_t)b * C_ * N_;

    f4v acc[4][4];
    #pragma unroll
    for (int mt = 0; mt < 4; ++mt)
        #pragma unroll
        for (int nt = 0; nt < 4; ++nt) acc[mt][nt] = (f4v){0.f, 0.f, 0.f, 0.f};

    for (int kc = 0; kc < 8; ++kc) {
        const int k0 = kc * 64;
        s8v wt[4];
        float4 xr[2][4];
        #pragma unroll
        for (int s = 0; s < 4; ++s) {
            int lin = t + 256 * s;
            int row = lin >> 3, g = lin & 7;
            wt[s] = *(const s8v*)&Wg[(size_t)row * 512 + k0 + g * 8];
        }
        #pragma unroll
        for (int ih2 = 0; ih2 < 2; ++ih2) {
            const float* xp = Xsrc + (size_t)(k0 + c4x * 4) * N_
                            + i0 + ih2 * 64 + i4x * 4;
            xr[ih2][0] = *(const float4*)(xp);
            xr[ih2][1] = *(const float4*)(xp + N_);
            xr[ih2][2] = *(const float4*)(xp + 2 * N_);
            xr[ih2][3] = *(const float4*)(xp + 3 * N_);
        }
        __syncthreads();                       // prior iter's frag reads done
        #pragma unroll
        for (int s = 0; s < 4; ++s) {
            int lin = t + 256 * s;
            int row = lin >> 3, g = lin & 7;
            int soff = row * 64 + ((g ^ (row & 7)) * 8);
            *(s8v*)&Ws[soff] = wt[s];
        }
        #pragma unroll
        for (int ih2 = 0; ih2 < 2; ++ih2) {
            #pragma unroll
            for (int j = 0; j < 4; ++j) {
                s4v pj = { (short)f2bf(xr[ih2][0][j]), (short)f2bf(xr[ih2][1][j]),
                           (short)f2bf(xr[ih2][2][j]), (short)f2bf(xr[ih2][3][j]) };
                *(s4v*)&Xs[(ih2 * 64 + i4x * 4 + j) * 72 + c4x * 4] = pj;
            }
        }
        __syncthreads();                       // tile staged
        #pragma unroll
        for (int kk = 0; kk < 2; ++kk) {
            const int gq = kk * 4 + quad;
            s8v af[4], bf[4];
            #pragma unroll
            for (int mt = 0; mt < 4; ++mt) {
                int r = mh + mt * 16 + col;
                af[mt] = *(const s8v*)&Ws[r * 64 + ((gq ^ (r & 7)) * 8)];
            }
            #pragma unroll
            for (int nt = 0; nt < 4; ++nt) {
                int r = nh + nt * 16 + col;
                bf[nt] = *(const s8v*)&Xs[r * 72 + gq * 8];
            }
            #pragma unroll
            for (int nt = 0; nt < 4; ++nt)
                #pragma unroll
                for (int mt = 0; mt < 4; ++mt)
                    acc[mt][nt] = __builtin_amdgcn_mfma_f32_16x16x32_bf16(
                        af[mt], bf[nt], acc[mt][nt], 0, 0, 0);
        }
    }

    // ---- epilogue ----
    const int mlo0 = mbase + mh;               // wave-uniform
    #pragma unroll
    for (int mt = 0; mt < 4; ++mt) {
        const int mlo = mlo0 + mt * 16;
        f4v bi = *(const f4v*)&biasb[mlo + quad * 4];
        if (mlo < 128 || mlo >= 640) {         // Q/K rows
            unsigned short* dst; int dbase;
            if (mlo < 64)       { dst = Q; dbase = mlo; }
            else if (mlo < 128) { dst = K; dbase = mlo - 64; }
            else if (mlo < 704) { dst = Q; dbase = 64 + (mlo - 640); }
            else                { dst = K; dbase = 64 + (mlo - 704); }
            #pragma unroll
            for (int nt = 0; nt < 4; ++nt) {
                int i = i0 + nh + nt * 16 + col;
                s4v pk = { (short)f2bf(acc[mt][nt][0] + bi[0]),
                           (short)f2bf(acc[mt][nt][1] + bi[1]),
                           (short)f2bf(acc[mt][nt][2] + bi[2]),
                           (short)f2bf(acc[mt][nt][3] + bi[3]) };
                *(s4v*)&dst[((size_t)b * N_ + i) * D_ + dbase + quad * 4] = pk;
            }
        } else {                               // V rows
            int c0 = mlo - 128 + quad * 4;
            #pragma unroll
            for (int nt = 0; nt < 4; ++nt) {
                int i = i0 + nh + nt * 16 + col;
                #pragma unroll
                for (int r = 0; r < 4; ++r)
                    V[((size_t)b * C_ + c0 + r) * N_ + i] =
                        f2bf(acc[mt][nt][r] + bi[r]);
            }
        }
    }
}

// ---------------------------------------------------------------------------
// MFMA flash attention — byte-exact R12 structure (best measured 117.2-119us,
// FROZEN). Tile-shape bracketing complete: 64i x 512c @ 2 blocks/CU is the
// optimum — bigger tiles blow the 124V+128A register budget (R8), c-split
// duplicates QK work (R13, +63%), i-halving halves staged-K/V reuse (R17,
// +58%), V-direct loses LDS-fed PV (R6/R7), fused-combine handshake pays
// cross-XCD fence + uncoalesced tail (R15, +130us).
//  * XCD group swizzle (FETCH 84->14MB), flat grid 512, id&7 = (b,jh).
//  * lgkm-only barriers; no vmcnt(0) drain; kt oldest-first; Vs write after
//    QK+softmax (vt wait covered); T5 setprio around PV cluster.
// Hazards (single Ks/Ps/Vs, barriers B1/B2/B3 per iter):
//   Ks w(B1..B2)/r(B2..B3): sep B2; r(tt) vs w(tt+1): sep B3+B1.
//   Vs,Ps w(B2..B3)/r(B3..B1'): sep B3; r(tt) vs w(tt+1): sep B1+B2.
// LDS: Ks 8704 | Ps 5120 | Vs 32768 | lred 512 = 47104 B -> 2 blocks/CU.
// ---------------------------------------------------------------------------
__global__ __launch_bounds__(256, 2) void attn_kernel(
    const unsigned short* __restrict__ Q, const unsigned short* __restrict__ K,
    const unsigned short* __restrict__ V,
    unsigned short* __restrict__ O_ws, float* __restrict__ l_ws)
{
    __shared__ __align__(16) unsigned short Ks[32 * 136];
    __shared__ __align__(16) unsigned short Ps[64 * 40];
    __shared__ __align__(16) unsigned short Vs[512 * 32];
    __shared__ float lred[2][64];

    const int id  = blockIdx.x;
    const int grp = id & 7;                 // XCD-affine group
    const int b   = grp & 3;
    const int jh  = grp >> 2;
    const int it  = id >> 3;                // i-tile 0..63
    const int i0  = it * 64;
    const int jb  = jh * 2048;
    const int t = threadIdx.x, w = t >> 6;
    const int lane = t & 63, col = lane & 15, quad = lane >> 4;
    const int ih = w & 1, jq = w >> 1;

    const unsigned short* Kg = K + (size_t)b * N_ * D_;
    const unsigned short* Vg = V + (size_t)b * C_ * N_;

    s8v qf[2][4];
    #pragma unroll
    for (int ig = 0; ig < 2; ++ig) {
        const unsigned short* qr =
            Q + ((size_t)b * N_ + i0 + ih * 32 + ig * 16 + col) * D_ + quad * 8;
        #pragma unroll
        for (int kk = 0; kk < 4; ++kk) qf[ig][kk] = *(const s8v*)(qr + kk * 32);
    }

    f4v accO[4][8];
    #pragma unroll
    for (int rt = 0; rt < 4; ++rt)
        #pragma unroll
        for (int ct = 0; ct < 8; ++ct) accO[rt][ct] = (f4v){0.f, 0.f, 0.f, 0.f};
    float lsum[2] = {0.f, 0.f};

    for (int tt = 0; tt < 64; ++tt) {
        const int j0 = jb + tt * 32;
        // issue loads: kt FIRST (oldest -> Ks write waits vmcnt(8) = kt only)
        s8v kt[2], vt[8];
        #pragma unroll
        for (int s = 0; s < 2; ++s) {
            int gi = t + 256 * s;
            kt[s] = *(const s8v*)&Kg[(size_t)(j0 + (gi >> 4)) * D_ + (gi & 15) * 8];
        }
        #pragma unroll
        for (int s = 0; s < 8; ++s) {
            int gi = t + 256 * s;
            vt[s] = *(const s8v*)&Vg[(size_t)(gi >> 2) * N_ + j0 + (gi & 3) * 8];
        }
        // B1: prior iter's Vs/Ps reads (and Ks reads) complete
        asm volatile("s_waitcnt lgkmcnt(0)" ::: "memory");
        __builtin_amdgcn_s_barrier();
        // stage K tile (vmcnt(8): waits kt, vt stays in flight)
        #pragma unroll
        for (int s = 0; s < 2; ++s) {
            int gi = t + 256 * s;
            *(s8v*)&Ks[(gi >> 4) * 136 + (gi & 15) * 8] = kt[s];
        }
        // B2: K tile staged
        asm volatile("s_waitcnt lgkmcnt(0)" ::: "memory");
        __builtin_amdgcn_s_barrier();
        // QK^T
        f4v s0 = (f4v){0.f, 0.f, 0.f, 0.f};
        f4v s1 = (f4v){0.f, 0.f, 0.f, 0.f};
        #pragma unroll
        for (int kk = 0; kk < 4; ++kk) {
            s8v kf = *(const s8v*)&Ks[(jq * 16 + col) * 136 + kk * 32 + quad * 8];
            s0 = __builtin_amdgcn_mfma_f32_16x16x32_bf16(kf, qf[0][kk], s0, 0, 0, 0);
            s1 = __builtin_amdgcn_mfma_f32_16x16x32_bf16(kf, qf[1][kk], s1, 0, 0, 0);
        }
        // softmax partials + pack P
        #pragma unroll
        for (int ig = 0; ig < 2; ++ig) {
            f4v sv = ig ? s1 : s0;
            s4v p; float ls = 0.f;
            #pragma unroll
            for (int r = 0; r < 4; ++r) {
                float e = __expf(sv[r]);
                ls += e;
                p[r] = (short)f2bf(e);
            }
            lsum[ig] += ls;
            *(s4v*)&Ps[(ih * 32 + ig * 16 + col) * 40 + jq * 16 + quad * 4] = p;
        }
        // stage V tile (vmcnt wait for vt covered by QK+softmax above)
        #pragma unroll
        for (int s = 0; s < 8; ++s) {
            int gi = t + 256 * s;
            int c = gi >> 2, g = gi & 3;
            int sw = (g + c + (c >> 2)) & 3;
            *(s8v*)&Vs[c * 32 + sw * 8] = vt[s];
        }
        // B3: P + V visible
        asm volatile("s_waitcnt lgkmcnt(0)" ::: "memory");
        __builtin_amdgcn_s_barrier();
        // P fragments + PV
        s8v pf[4];
        #pragma unroll
        for (int rt = 0; rt < 4; ++rt)
            pf[rt] = *(const s8v*)&Ps[(rt * 16 + col) * 40 + quad * 8];
        __builtin_amdgcn_s_setprio(1);
        #pragma unroll
        for (int ct = 0; ct < 8; ++ct) {
            int row = w * 128 + ct * 16 + col;
            int sw = (quad + row + (row >> 2)) & 3;
            s8v vf = *(const s8v*)&Vs[row * 32 + sw * 8];
            #pragma unroll
            for (int rt = 0; rt < 4; ++rt)
                accO[rt][ct] = __builtin_amdgcn_mfma_f32_16x16x32_bf16(pf[rt], vf, accO[rt][ct], 0, 0, 0);
        }
        __builtin_amdgcn_s_setprio(0);
    }

    #pragma unroll
    for (int ig = 0; ig < 2; ++ig) {
        float v = lsum[ig];
        v += __shfl_xor(v, 16);
        v += __shfl_xor(v, 32);
        if (quad == 0) lred[jq][ih * 32 + ig * 16 + col] = v;
    }
    __syncthreads();
    if (t < 64)
        l_ws[((size_t)jh * B_ + b) * N_ + i0 + t] = lred[0][t] + lred[1][t];

    const size_t wbase =
        ((((size_t)jh * B_ + b) * 64 + it) * 4 + w) * 8192;
    #pragma unroll
    for (int ct = 0; ct < 8; ++ct)
        #pragma unroll
        for (int rt = 0; rt < 4; ++rt) {
            s4v pk = { (short)f2bf(accO[rt][ct][0]), (short)f2bf(accO[rt][ct][1]),
                       (short)f2bf(accO[rt][ct][2]), (short)f2bf(accO[rt][ct][3]) };
            *(s4v*)&O_ws[wbase + (size_t)(ct * 4 + rt) * 256 + lane * 4] = pk;
        }
}

// ---------------------------------------------------------------------------
// Combine: out = gamma * (O0+O1)/(l0+l1) + x_rgb.  (Byte-exact R12 version:
// dense O_ws reads, 2 ct-segments per thread, grid 4096.)
//   O_ws[wbase(jh,b,it,w) + (ct*4+rt)*256 + (qd*16+col)*4 + r]
//     = O[it*64 + rt*16 + qd*4 + r][w*128 + ct*16 + col]
// ---------------------------------------------------------------------------
__global__ __launch_bounds__(256) void combine_kernel(
    const unsigned short* __restrict__ O_ws, const float* __restrict__ l_ws,
    const float* __restrict__ x_rgb, const float* __restrict__ gamma,
    float* __restrict__ out)
{
    const size_t half = (size_t)B_ * 64 * 4 * 8192;   // elems per j-half
    const int bx = blockIdx.x;                        // 4096 blocks
    const int ct0 = (bx & 3) * 2;                     // 2 ct per block
    const int w  = (bx >> 2) & 3;
    const int it = (bx >> 4) & 63;
    const int b  = bx >> 10;
    const int t  = threadIdx.x;
    const int rt = t >> 6, l = t & 63;
    const int c_sub = l >> 2, qd = l & 3;

    const int i = it * 64 + rt * 16 + qd * 4;         // 4 consecutive i
    float4 l0 = *(const float4*)&l_ws[(size_t)b * N_ + i];
    float4 l1 = *(const float4*)&l_ws[(size_t)(B_ + b) * N_ + i];
    float4 linv = { 1.f / (l0.x + l1.x), 1.f / (l0.y + l1.y),
                    1.f / (l0.z + l1.z), 1.f / (l0.w + l1.w) };
    float g = gamma[0];

    #pragma unroll
    for (int u = 0; u < 2; ++u) {
        const int ct = ct0 + u;
        const int c = w * 128 + ct * 16 + c_sub;
        const size_t seg = (((size_t)b * 64 + it) * 4 + w) * 8192
                         + (size_t)(ct * 4 + rt) * 256 + (qd * 16 + c_sub) * 4;
        s4v o0 = *(const s4v*)&O_ws[seg];
        s4v o1 = *(const s4v*)&O_ws[half + seg];
        size_t base = ((size_t)b * C_ + c) * N_ + i;
        float4 x4 = *(const float4*)&x_rgb[base];
        float4 r;
        r.x = g * (bf2f((unsigned short)o0[0]) + bf2f((unsigned short)o1[0])) * linv.x + x4.x;
        r.y = g * (bf2f((unsigned short)o0[1]) + bf2f((unsigned short)o1[1])) * linv.y + x4.y;
        r.z = g * (bf2f((unsigned short)o0[2]) + bf2f((unsigned short)o1[2])) * linv.z + x4.z;
        r.w = g * (bf2f((unsigned short)o0[3]) + bf2f((unsigned short)o1[3])) * linv.w + x4.w;
        *(float4*)&out[base] = r;
    }
}

// ---------------------------------------------------------------------------
extern "C" void kernel_launch(void* const* d_in, const int* in_sizes, int n_in,
                              void* d_out, int out_size, void* d_ws, size_t ws_size,
                              hipStream_t stream) {
    (void)in_sizes; (void)n_in; (void)out_size; (void)ws_size;
    const float* x_rgb = (const float*)d_in[0];
    const float* x_dep = (const float*)d_in[1];
    const float* Wq    = (const float*)d_in[2];
    const float* bq    = (const float*)d_in[3];
    const float* Wk    = (const float*)d_in[4];
    const float* bk    = (const float*)d_in[5];
    const float* Wdq   = (const float*)d_in[6];
    const float* bdq   = (const float*)d_in[7];
    const float* Wdk   = (const float*)d_in[8];
    const float* bdk   = (const float*)d_in[9];
    const float* Wv    = (const float*)d_in[10];
    const float* bv    = (const float*)d_in[11];
    const float* gamma = (const float*)d_in[12];
    float* out = (float*)d_out;

    // ws: Q 4MB | K 4MB | V 16.8MB | Wb 768KB | biasb 4KB f32 |
    // O_ws 33.5MB | l_ws 128KB f32.  Total ~59 MB.
    unsigned short* Q     = (unsigned short*)d_ws;
    unsigned short* K     = Q + (size_t)B_ * N_ * D_;
    unsigned short* V     = K + (size_t)B_ * N_ * D_;
    unsigned short* Wb    = V + (size_t)B_ * C_ * N_;
    float*          biasb = (float*)(Wb + 768 * 512);
    unsigned short* O_ws  = (unsigned short*)(biasb + 1024);
    float*          l_ws  = (float*)(O_ws + (size_t)2 * B_ * C_ * N_);

    cvt_w_kernel<<<dim3(192), 256, 0, stream>>>(
        Wq, bq, Wk, bk, Wdq, bdq, Wdk, bdk, Wv, bv, Wb, biasb);
    gemm_kernel<<<dim3(128, 6), 256, 0, stream>>>(Wb, biasb, x_rgb, x_dep, Q, K, V);
    attn_kernel<<<dim3(512), 256, 0, stream>>>(Q, K, V, O_ws, l_ws);
    combine_kernel<<<dim3(4096), 256, 0, stream>>>(O_ws, l_ws, x_rgb, gamma, out);
}